// Round 3
// baseline (311.429 us; speedup 1.0000x reference)
//
#include <hip/hip_runtime.h>
#include <math.h>

#define NB   262144   // batch (tokens)
#define DD   512      // d_routing
#define NG   4        // groups
#define NGS  4        // group size
#define NOUT 20       // 4 group logits + 16 in-group logits

// Native clang vector type (HIP's float4 is a struct; the nontemporal builtin
// wants a real vector-of-float pointer).
typedef float f32x4 __attribute__((ext_vector_type(4)));

// No LDS at all:
//  - weights are read through wave-uniform addresses -> compiler scalarizes to
//    s_load (SGPR operand of v_fmac), served by K$/L2. Zero LDS-pipe, zero VGPR.
//  - x is streamed nontemporal (no L1 pollution), 4x float4 back-to-back per
//    64B line so same-line L1 misses merge in the MSHRs.
//  - low VGPR -> 8 waves/SIMD (32 waves/CU) to hide the scattered-row latency.
__global__ __launch_bounds__(256, 8) void router_k(
    const float* __restrict__ x,        // [NB, DD]
    const float* __restrict__ group_w,  // [NG, DD]
    const float* __restrict__ group_b,  // [NG]
    const float* __restrict__ in_w,     // [NG*NGS, DD]
    const float* __restrict__ in_b,     // [NG, NGS]
    const int*   __restrict__ experts,  // [NG, NGS]
    float*       __restrict__ out)      // [2*NB*2]: indices then weights, fp32
{
    const int t = blockIdx.x * 256 + threadIdx.x;  // one token per thread
    const float* xr = x + (size_t)t * DD;

    float acc[NOUT];
#pragma unroll
    for (int o = 0; o < NOUT; ++o) acc[o] = 0.f;

    for (int dd = 0; dd < DD; dd += 16) {
        // 64B of this thread's row: 4 consecutive float4 loads (MSHR-mergeable)
        f32x4 xv0 = __builtin_nontemporal_load(
            reinterpret_cast<const f32x4*>(xr + dd));
        f32x4 xv1 = __builtin_nontemporal_load(
            reinterpret_cast<const f32x4*>(xr + dd + 4));
        f32x4 xv2 = __builtin_nontemporal_load(
            reinterpret_cast<const f32x4*>(xr + dd + 8));
        f32x4 xv3 = __builtin_nontemporal_load(
            reinterpret_cast<const f32x4*>(xr + dd + 12));
        float xv[16] = {xv0.x, xv0.y, xv0.z, xv0.w,
                        xv1.x, xv1.y, xv1.z, xv1.w,
                        xv2.x, xv2.y, xv2.z, xv2.w,
                        xv3.x, xv3.y, xv3.z, xv3.w};

        // Weight addresses are wave-uniform (o is an unroll constant, dd is a
        // uniform loop var) -> scalar loads, contiguous 64B per (o, dd) pair.
#pragma unroll
        for (int o = 0; o < NOUT; ++o) {
            const float* wr = (o < NG) ? (group_w + o * DD)
                                       : (in_w + (o - NG) * DD);
            float a = acc[o];
#pragma unroll
            for (int j = 0; j < 16; ++j)
                a = fmaf(xv[j], wr[dd + j], a);
            acc[o] = a;
        }
    }

    // ---- group argmax (first-max tie-break, matches jnp.argmax) ----
    float gl[NG];
#pragma unroll
    for (int g = 0; g < NG; ++g) gl[g] = acc[g] + group_b[g];
    int bg = 0;
    float bv = gl[0];
#pragma unroll
    for (int g = 1; g < NG; ++g)
        if (gl[g] > bv) { bv = gl[g]; bg = g; }

    // ---- select chosen group's in-logits without runtime indexing ----
    float il[NGS];
#pragma unroll
    for (int k = 0; k < NGS; ++k) il[k] = 0.f;
#pragma unroll
    for (int g = 0; g < NG; ++g) {
        const bool sel = (g == bg);
#pragma unroll
        for (int k = 0; k < NGS; ++k)
            il[k] = sel ? acc[NG + g * NGS + k] : il[k];
    }
#pragma unroll
    for (int k = 0; k < NGS; ++k) il[k] += in_b[bg * NGS + k];

    // ---- softmax (fp32, subtract-max, matches jax.nn.softmax) ----
    float m = fmaxf(fmaxf(il[0], il[1]), fmaxf(il[2], il[3]));
    float p[NGS];
    float s = 0.f;
#pragma unroll
    for (int k = 0; k < NGS; ++k) { p[k] = expf(il[k] - m); s += p[k]; }
    const float inv = 1.0f / s;
#pragma unroll
    for (int k = 0; k < NGS; ++k) p[k] *= inv;

    // ---- top-2 on probs (descending, lower-index-on-tie, matches lax.top_k) ----
    int i1 = 0;
    float v1 = p[0];
#pragma unroll
    for (int k = 1; k < NGS; ++k)
        if (p[k] > v1) { v1 = p[k]; i1 = k; }
    int i2 = -1;
    float v2 = -3.0e38f;
#pragma unroll
    for (int k = 0; k < NGS; ++k)
        if (k != i1 && p[k] > v2) { v2 = p[k]; i2 = k; }

    const int id1 = experts[bg * NGS + i1];
    const int id2 = experts[bg * NGS + i2];

    // ---- write: [expert_indices (as f32) | top_weights], coalesced float2 ----
    float2* outi = reinterpret_cast<float2*>(out);
    float2* outw = reinterpret_cast<float2*>(out + (size_t)NB * 2);
    outi[t] = make_float2((float)id1, (float)id2);
    outw[t] = make_float2(v1, v2);
}

extern "C" void kernel_launch(void* const* d_in, const int* in_sizes, int n_in,
                              void* d_out, int out_size, void* d_ws, size_t ws_size,
                              hipStream_t stream) {
    const float* x  = (const float*)d_in[0];
    const float* gw = (const float*)d_in[1];
    const float* gb = (const float*)d_in[2];
    const float* iw = (const float*)d_in[3];
    const float* ib = (const float*)d_in[4];
    const int*   et = (const int*)d_in[5];
    float* out = (float*)d_out;

    router_k<<<dim3(NB / 256), dim3(256), 0, stream>>>(x, gw, gb, iw, ib, et, out);
}

// Round 4
// 179.914 us; speedup vs baseline: 1.7310x; 1.7310x over previous
//
#include <hip/hip_runtime.h>
#include <math.h>

#define NB   262144   // batch (tokens)
#define DD   512      // d_routing
#define NG   4        // groups
#define NGS  4        // group size
#define NOUT 20       // 4 group logits + 16 in-group logits
#define T    2        // tokens per thread (amortizes weight LDS broadcasts)

// Round-1 structure (LDS fp32 weights + plain temporal float4 x loads) with
// T=2 tokens/thread: each broadcast ds_read_b128 of weights now feeds 16 FMAs
// instead of 8, halving the LDS-return-bus time (the round-1 limiter) to
// ~68us/CU, below the 81us HBM floor.
__global__ __launch_bounds__(256, 4) void router_k(
    const float* __restrict__ x,        // [NB, DD]
    const float* __restrict__ group_w,  // [NG, DD]
    const float* __restrict__ group_b,  // [NG]
    const float* __restrict__ in_w,     // [NG*NGS, DD]
    const float* __restrict__ in_b,     // [NG, NGS]
    const int*   __restrict__ experts,  // [NG, NGS]
    float*       __restrict__ out)      // [2*NB*2]: indices then weights, fp32
{
    __shared__ float wlds[NOUT * DD];   // 40 KB: rows 0..3 group_w, 4..19 in_w
    {
        const float4* gw4 = reinterpret_cast<const float4*>(group_w);
        const float4* iw4 = reinterpret_cast<const float4*>(in_w);
        float4* wl4 = reinterpret_cast<float4*>(wlds);
        for (int i = threadIdx.x; i < (NG * DD) / 4; i += 256)
            wl4[i] = gw4[i];
        for (int i = threadIdx.x; i < (NG * NGS * DD) / 4; i += 256)
            wl4[(NG * DD) / 4 + i] = iw4[i];
    }
    __syncthreads();

    // Block covers 512 tokens; this thread owns t0 and t0+256.
    const int t0 = blockIdx.x * (256 * T) + threadIdx.x;
    const float* xr0 = x + (size_t)t0 * DD;
    const float* xr1 = x + (size_t)(t0 + 256) * DD;

    float acc0[NOUT], acc1[NOUT];
#pragma unroll
    for (int o = 0; o < NOUT; ++o) { acc0[o] = 0.f; acc1[o] = 0.f; }

    for (int dd = 0; dd < DD; dd += 8) {
        // 32B per token row (2 consecutive float4 -> same/adjacent line, L1 reuse)
        const float4 x0a = *reinterpret_cast<const float4*>(xr0 + dd);
        const float4 x0b = *reinterpret_cast<const float4*>(xr0 + dd + 4);
        const float4 x1a = *reinterpret_cast<const float4*>(xr1 + dd);
        const float4 x1b = *reinterpret_cast<const float4*>(xr1 + dd + 4);

#pragma unroll
        for (int o = 0; o < NOUT; ++o) {
            const float4 wa = *reinterpret_cast<const float4*>(&wlds[o * DD + dd]);
            const float4 wb = *reinterpret_cast<const float4*>(&wlds[o * DD + dd + 4]);
            float a0 = acc0[o];
            float a1 = acc1[o];
            a0 = fmaf(x0a.x, wa.x, a0); a1 = fmaf(x1a.x, wa.x, a1);
            a0 = fmaf(x0a.y, wa.y, a0); a1 = fmaf(x1a.y, wa.y, a1);
            a0 = fmaf(x0a.z, wa.z, a0); a1 = fmaf(x1a.z, wa.z, a1);
            a0 = fmaf(x0a.w, wa.w, a0); a1 = fmaf(x1a.w, wa.w, a1);
            a0 = fmaf(x0b.x, wb.x, a0); a1 = fmaf(x1b.x, wb.x, a1);
            a0 = fmaf(x0b.y, wb.y, a0); a1 = fmaf(x1b.y, wb.y, a1);
            a0 = fmaf(x0b.z, wb.z, a0); a1 = fmaf(x1b.z, wb.z, a1);
            a0 = fmaf(x0b.w, wb.w, a0); a1 = fmaf(x1b.w, wb.w, a1);
            acc0[o] = a0;
            acc1[o] = a1;
        }
    }

    // ---- epilogue for both tokens ----
    float2* outi = reinterpret_cast<float2*>(out);
    float2* outw = reinterpret_cast<float2*>(out + (size_t)NB * 2);

#pragma unroll
    for (int tk = 0; tk < T; ++tk) {
        const float* acc = (tk == 0) ? acc0 : acc1;   // tk is an unroll constant
        const int t = t0 + tk * 256;

        // group argmax (first-max tie-break, matches jnp.argmax)
        float gl[NG];
#pragma unroll
        for (int g = 0; g < NG; ++g) gl[g] = acc[g] + group_b[g];
        int bg = 0;
        float bv = gl[0];
#pragma unroll
        for (int g = 1; g < NG; ++g)
            if (gl[g] > bv) { bv = gl[g]; bg = g; }

        // select chosen group's in-logits without runtime indexing
        float il[NGS];
#pragma unroll
        for (int k = 0; k < NGS; ++k) il[k] = 0.f;
#pragma unroll
        for (int g = 0; g < NG; ++g) {
            const bool sel = (g == bg);
#pragma unroll
            for (int k = 0; k < NGS; ++k)
                il[k] = sel ? acc[NG + g * NGS + k] : il[k];
        }
#pragma unroll
        for (int k = 0; k < NGS; ++k) il[k] += in_b[bg * NGS + k];

        // softmax (fp32, subtract-max)
        float m = fmaxf(fmaxf(il[0], il[1]), fmaxf(il[2], il[3]));
        float p[NGS];
        float s = 0.f;
#pragma unroll
        for (int k = 0; k < NGS; ++k) { p[k] = expf(il[k] - m); s += p[k]; }
        const float inv = 1.0f / s;
#pragma unroll
        for (int k = 0; k < NGS; ++k) p[k] *= inv;

        // top-2 (descending, lower-index-on-tie, matches lax.top_k)
        int i1 = 0;
        float v1 = p[0];
#pragma unroll
        for (int k = 1; k < NGS; ++k)
            if (p[k] > v1) { v1 = p[k]; i1 = k; }
        int i2 = -1;
        float v2 = -3.0e38f;
#pragma unroll
        for (int k = 0; k < NGS; ++k)
            if (k != i1 && p[k] > v2) { v2 = p[k]; i2 = k; }

        const int id1 = experts[bg * NGS + i1];
        const int id2 = experts[bg * NGS + i2];

        outi[t] = make_float2((float)id1, (float)id2);
        outw[t] = make_float2(v1, v2);
    }
}

extern "C" void kernel_launch(void* const* d_in, const int* in_sizes, int n_in,
                              void* d_out, int out_size, void* d_ws, size_t ws_size,
                              hipStream_t stream) {
    const float* x  = (const float*)d_in[0];
    const float* gw = (const float*)d_in[1];
    const float* gb = (const float*)d_in[2];
    const float* iw = (const float*)d_in[3];
    const float* ib = (const float*)d_in[4];
    const int*   et = (const int*)d_in[5];
    float* out = (float*)d_out;

    router_k<<<dim3(NB / (256 * T)), dim3(256), 0, stream>>>(x, gw, gb, iw, ib, et, out);
}

// Round 5
// 170.765 us; speedup vs baseline: 1.8237x; 1.0536x over previous
//
#include <hip/hip_runtime.h>
#include <math.h>

#define NB   262144   // batch (tokens)
#define DD   512      // d_routing
#define NG   4        // groups
#define NGS  4        // group size
#define NOUT 20       // 4 group logits + 16 in-group logits

#define TPB        256          // threads per block
#define TOKS       512          // tokens per block (T=2 per thread)
#define CH         32           // floats of D per staged chunk (= one 128B line/token)
#define NCHUNK     (DD / CH)    // 16
#define GRP_FLOATS 260          // 8 tokens * 32 floats + 4 pad floats (bank spread)
#define NGRP       (TOKS / 8)   // 64 staging groups per chunk
#define WROWS      24           // 20 weight rows padded to 24 (3 full instructions)

typedef float f32x4 __attribute__((ext_vector_type(4)));

// global_load_lds: LDS dest is wave-uniform base + lane*16B (linear);
// global src is per-lane. Casts go generic -> AS1/AS3 explicitly.
#define GLOAD_LDS16(gsrc, ldst)                                                \
    __builtin_amdgcn_global_load_lds(                                          \
        (const __attribute__((address_space(1))) unsigned int*)(gsrc),         \
        (__attribute__((address_space(3))) unsigned int*)(ldst), 16, 0, 0)

// x is staged through LDS with fully line-coalesced global_load_lds (8 tokens
// x one full 128B line per instruction), killing the L1-thrash refill traffic
// that limited the direct per-thread-row loads. Weights: per-chunk 3KB slice
// staged the same way, consumed as wave-uniform broadcasts. 68KB LDS/block ->
// 2 blocks/CU; the second block's compute covers this block's staging latency.
__global__ __launch_bounds__(TPB, 2) void router_k(
    const float* __restrict__ x,        // [NB, DD]
    const float* __restrict__ group_w,  // [NG, DD]
    const float* __restrict__ group_b,  // [NG]
    const float* __restrict__ in_w,     // [NG*NGS, DD]
    const float* __restrict__ in_b,     // [NG, NGS]
    const int*   __restrict__ experts,  // [NG, NGS]
    float*       __restrict__ out)      // [2*NB*2]: indices then weights, fp32
{
    __shared__ float xbuf[NGRP * GRP_FLOATS];  // 66560 B
    __shared__ float wbuf[WROWS * CH];         //  3072 B

    const int tid  = threadIdx.x;
    const int wid  = tid >> 6;
    const int lane = tid & 63;
    const int tok0 = blockIdx.x * TOKS;

    const int lrow = lane >> 3;        // token-in-group for staging
    const int lcol = (lane & 7) * 4;   // float offset within 128B line

    // This thread's two tokens: tid and tid+256.
    const float* xb0 = &xbuf[(tid >> 3) * GRP_FLOATS + (tid & 7) * CH];
    const float* xb1 = xb0 + 32 * GRP_FLOATS;

    float acc0[NOUT], acc1[NOUT];
#pragma unroll
    for (int o = 0; o < NOUT; ++o) { acc0[o] = 0.f; acc1[o] = 0.f; }

    for (int ch = 0; ch < NCHUNK; ++ch) {
        const int dd = ch * CH;

        // ---- stage x chunk: wave wid issues groups k = wid*16 .. wid*16+15.
        // Each instruction: 8 tokens x 128B full lines, LDS dest linear 1KB.
#pragma unroll
        for (int kk = 0; kk < 16; ++kk) {
            const int k = wid * 16 + kk;
            const float* src =
                x + ((size_t)(tok0 + k * 8 + lrow)) * DD + dd + lcol;
            GLOAD_LDS16(src, &xbuf[k * GRP_FLOATS]);
        }

        // ---- stage w chunk (20 rows x 32 floats): wave 0, 3 instructions.
        if (wid == 0) {
#pragma unroll
            for (int m = 0; m < 3; ++m) {
                int R = m * 8 + lrow;
                if (R > 19) R = 19;  // dup row 19 into pad rows 20..23
                const float* wr = (R < NG) ? (group_w + R * DD)
                                           : (in_w + (R - NG) * DD);
                GLOAD_LDS16(wr + dd + lcol, &wbuf[m * 8 * CH]);
            }
        }

        __syncthreads();  // compiler inserts vmcnt(0) drain before s_barrier

        // ---- compute: per granule g, 2 x-reads (own tokens) + 20 broadcasts.
#pragma unroll
        for (int g = 0; g < 8; ++g) {
            const f32x4 x0 = *reinterpret_cast<const f32x4*>(xb0 + g * 4);
            const f32x4 x1 = *reinterpret_cast<const f32x4*>(xb1 + g * 4);
#pragma unroll
            for (int o = 0; o < NOUT; ++o) {
                const f32x4 w =
                    *reinterpret_cast<const f32x4*>(&wbuf[o * CH + g * 4]);
                float a0 = acc0[o];
                float a1 = acc1[o];
                a0 = fmaf(x0.x, w.x, a0); a1 = fmaf(x1.x, w.x, a1);
                a0 = fmaf(x0.y, w.y, a0); a1 = fmaf(x1.y, w.y, a1);
                a0 = fmaf(x0.z, w.z, a0); a1 = fmaf(x1.z, w.z, a1);
                a0 = fmaf(x0.w, w.w, a0); a1 = fmaf(x1.w, w.w, a1);
                acc0[o] = a0;
                acc1[o] = a1;
            }
        }

        __syncthreads();  // all reads done before next chunk overwrites
    }

    // ---- epilogue for both tokens ----
    float2* outi = reinterpret_cast<float2*>(out);
    float2* outw = reinterpret_cast<float2*>(out + (size_t)NB * 2);

#pragma unroll
    for (int tk = 0; tk < 2; ++tk) {
        const float* acc = (tk == 0) ? acc0 : acc1;  // unroll-constant select
        const int t = tok0 + tid + tk * 256;

        // group argmax (first-max tie-break, matches jnp.argmax)
        float gl[NG];
#pragma unroll
        for (int g = 0; g < NG; ++g) gl[g] = acc[g] + group_b[g];
        int bg = 0;
        float bv = gl[0];
#pragma unroll
        for (int g = 1; g < NG; ++g)
            if (gl[g] > bv) { bv = gl[g]; bg = g; }

        // select chosen group's in-logits without runtime indexing
        float il[NGS];
#pragma unroll
        for (int k = 0; k < NGS; ++k) il[k] = 0.f;
#pragma unroll
        for (int g = 0; g < NG; ++g) {
            const bool sel = (g == bg);
#pragma unroll
            for (int k = 0; k < NGS; ++k)
                il[k] = sel ? acc[NG + g * NGS + k] : il[k];
        }
#pragma unroll
        for (int k = 0; k < NGS; ++k) il[k] += in_b[bg * NGS + k];

        // softmax (fp32, subtract-max)
        float m = fmaxf(fmaxf(il[0], il[1]), fmaxf(il[2], il[3]));
        float p[NGS];
        float s = 0.f;
#pragma unroll
        for (int k = 0; k < NGS; ++k) { p[k] = expf(il[k] - m); s += p[k]; }
        const float inv = 1.0f / s;
#pragma unroll
        for (int k = 0; k < NGS; ++k) p[k] *= inv;

        // top-2 (descending, lower-index-on-tie, matches lax.top_k)
        int i1 = 0;
        float v1 = p[0];
#pragma unroll
        for (int k = 1; k < NGS; ++k)
            if (p[k] > v1) { v1 = p[k]; i1 = k; }
        int i2 = -1;
        float v2 = -3.0e38f;
#pragma unroll
        for (int k = 0; k < NGS; ++k)
            if (k != i1 && p[k] > v2) { v2 = p[k]; i2 = k; }

        const int id1 = experts[bg * NGS + i1];
        const int id2 = experts[bg * NGS + i2];

        outi[t] = make_float2((float)id1, (float)id2);
        outw[t] = make_float2(v1, v2);
    }
}

extern "C" void kernel_launch(void* const* d_in, const int* in_sizes, int n_in,
                              void* d_out, int out_size, void* d_ws, size_t ws_size,
                              hipStream_t stream) {
    const float* x  = (const float*)d_in[0];
    const float* gw = (const float*)d_in[1];
    const float* gb = (const float*)d_in[2];
    const float* iw = (const float*)d_in[3];
    const float* ib = (const float*)d_in[4];
    const int*   et = (const int*)d_in[5];
    float* out = (float*)d_out;

    router_k<<<dim3(NB / TOKS), dim3(TPB), 0, stream>>>(x, gw, gb, iw, ib, et, out);
}